// Round 4
// baseline (861.150 us; speedup 1.0000x reference)
//
#include <hip/hip_runtime.h>

// v5: one 1024-thread workgroup per group n (1024 groups of 16ch x 64x64).
// Same pass structure + numerics as v4 (stage | means | gates | A: x1 sum/sq |
// B: single chunked conv sweep, Z1/Z3/S3, x3 bf16 in-place over dead x rows |
// C: final). Changes: ALL global accesses are now 256B-contiguous per wave
// instruction (stage: lane=w channel-quad loads; pass C: pixel-contiguous
// mapping with 16 coalesced loads+stores) to kill the 32-64B-granule HBM
// write-amplification seen in v4 (WRITE_SIZE 467MB vs 268MB logical).

typedef short bf16x8 __attribute__((ext_vector_type(8)));
typedef short bf16x4 __attribute__((ext_vector_type(4)));
typedef float f32x4 __attribute__((ext_vector_type(4)));
typedef unsigned int u32x2 __attribute__((ext_vector_type(2)));
typedef unsigned int u32x4 __attribute__((ext_vector_type(4)));

__device__ __forceinline__ unsigned short f2bf(float f) {
    union { float f; unsigned int u; } v; v.f = f;
    unsigned int u = v.u;
    u += 0x7fffu + ((u >> 16) & 1u);          // RNE
    return (unsigned short)(u >> 16);
}
__device__ __forceinline__ float bf2f(unsigned short h) {
    union { unsigned int u; float f; } v; v.u = ((unsigned int)h) << 16;
    return v.f;
}
__device__ __forceinline__ float sigm(float v) { return 1.0f / (1.0f + __expf(-v)); }

// LDS x layout: [h1][blk][w1][8ch] bf16; blk = c>>3. (identical to proven v1/v4)
#define XIDX(h1,w1,c) ((((h1)*2 + ((c)>>3))*66 + (w1))*8 + ((c)&7))

__global__ __launch_bounds__(1024) void ema_fused(
    const float* __restrict__ x,
    const float* __restrict__ w1, const float* __restrict__ b1,
    const float* __restrict__ wh, const float* __restrict__ bh,
    const float* __restrict__ ww, const float* __restrict__ bw,
    const float* __restrict__ w3, const float* __restrict__ b3,
    const float* __restrict__ gamma, const float* __restrict__ beta,
    float* __restrict__ out)
{
    const int n    = blockIdx.x;
    const int tid  = threadIdx.x;
    const int lane = tid & 63;
    const int wv   = tid >> 6;       // wave 0..15
    const int qd   = lane >> 4;      // quad 0..3
    const int col  = lane & 15;

    const float* xg = x + (size_t)n * 65536;
    float* ob = out + (size_t)n * 65536;

    __shared__ __align__(16) unsigned short sX[69696];   // 139392 B padded bf16 x (later: x3 in slots h-2)
    __shared__ __align__(16) unsigned short sXtra[2048]; // x3 rows 0,1: [h][w][16c] bf16
    __shared__ __align__(16) float sG[2048];             // means -> y2 -> gates: ah[c*64+h], aw[1024+c*64+w]
    __shared__ float sRedA[256], sRedB[256], sRedC[256];
    __shared__ float sS1[16], sSQ[16], sV1[16];
    __shared__ float sA[16], sB1[16], sQ1[16], sQ3[16];
    __shared__ float sScal[2];

    // ---- Phase 1: zero-pad (b128) + stage x -> LDS bf16, 256B-coalesced ----
    {
        u32x4 zz = {0u, 0u, 0u, 0u};
        for (int i = tid; i < 8712; i += 1024) ((u32x4*)sX)[i] = zz;
    }
    __syncthreads();
    {
        const int rblk = wv >> 2;        // 0..3 (rows rblk*16 .. +15)
        const int cq   = wv & 3;         // 0..3 (channels cq*4 .. +3)
        const int c0s  = cq * 4;
        const float* xb = xg + c0s*4096 + lane;
        #pragma unroll 4
        for (int rr = 0; rr < 16; ++rr) {
            int r = rblk*16 + rr;
            float v0 = xb[r*64];             // each: 64 consecutive floats = 256B/instr
            float v1 = xb[r*64 + 4096];
            float v2 = xb[r*64 + 8192];
            float v3 = xb[r*64 + 12288];
            u32x2 pk;
            pk[0] = (unsigned int)f2bf(v0) | ((unsigned int)f2bf(v1) << 16);
            pk[1] = (unsigned int)f2bf(v2) | ((unsigned int)f2bf(v3) << 16);
            *(u32x2*)&sX[XIDX(r+1, lane+1, c0s)] = pk;
        }
    }

    // ---- conv weight fragments (proven v1 mapping; global loads overlap barrier) ----
    bf16x8 afr[5];
    int offs[5];
    #pragma unroll
    for (int mm = 0; mm < 5; ++mm) {
        int t = 2*mm + (qd >> 1);
        #pragma unroll
        for (int j = 0; j < 8; ++j) {
            int i = ((qd & 1) << 3) + j;
            float v = (t <= 8) ? w3[(col*16 + i)*9 + t] : 0.0f;
            afr[mm][j] = (short)f2bf(v);
        }
        int tb = (t > 8) ? 8 : t;
        int dy = tb/3 - 1, dx = tb - (tb/3)*3 - 1;
        offs[mm] = dy*1056 + dx*8;          // h1 coeff 1056, w1 coeff 8 (ushort units)
    }
    float b3v[4];
    #pragma unroll
    for (int r = 0; r < 4; ++r) b3v[r] = b3[qd*4 + r];
    __syncthreads();

    // ---- Phase 2: row means (x_h) and col means (x_w) ----
    if (tid < 512) {
        int half = tid & 1;
        int part = (tid >> 1) & 1;
        int idx  = tid >> 2;          // 0..127
        int isCol = idx >> 6;         // 0: mean over w at r=idx ; 1: mean over h at w=idx-64
        int rc = idx & 63;
        float acc[8] = {0,0,0,0,0,0,0,0};
        for (int t = part*32; t < part*32 + 32; ++t) {
            int hh = isCol ? (t + 1) : (rc + 1);
            int wwi = isCol ? (rc + 1) : (t + 1);
            const bf16x8 v = *(const bf16x8*)&sX[XIDX(hh, wwi, half*8)];
            #pragma unroll
            for (int j = 0; j < 8; ++j) acc[j] += bf2f((unsigned short)v[j]);
        }
        #pragma unroll
        for (int j = 0; j < 8; ++j) acc[j] += __shfl_xor(acc[j], 2, 64);
        if (part == 0) {
            #pragma unroll
            for (int j = 0; j < 8; ++j)
                sG[isCol*1024 + (half*8+j)*64 + rc] = acc[j] * (1.0f/64.0f);
        }
    }
    __syncthreads();

    // ---- Phase 3a: y2[o][q] = silu(W1 @ [xh;xw] + b1), q in [0,128) ----
    {
        float yv[2];
        #pragma unroll
        for (int j = 0; j < 2; ++j) {
            int tsk = tid + j*1024;            // 0..2047
            int o = tsk & 15, q = tsk >> 4;
            float acc = b1[o];
            #pragma unroll
            for (int i = 0; i < 16; ++i)
                acc += w1[o*16 + i] * sG[((q>>6)<<10) + i*64 + (q & 63)];
            yv[j] = acc * sigm(acc);
        }
        __syncthreads();
        #pragma unroll
        for (int j = 0; j < 2; ++j) {
            int tsk = tid + j*1024;
            int o = tsk & 15, q = tsk >> 4;
            sG[o*128 + q] = yv[j];
        }
    }
    __syncthreads();
    // ---- Phase 3b: a_h = sigmoid(Wh@y_h+bh), a_w = sigmoid(Ww@y_w+bw) ----
    {
        float av[2];
        #pragma unroll
        for (int j = 0; j < 2; ++j) {
            int tsk = tid + j*1024;
            int kind = tsk >> 10;              // 0: ah, 1: aw
            int o = tsk & 15, pos = (tsk >> 4) & 63;
            const float* wm = kind ? ww : wh;
            float acc = kind ? bw[o] : bh[o];
            #pragma unroll
            for (int i = 0; i < 16; ++i)
                acc += wm[o*16 + i] * sG[i*128 + kind*64 + pos];
            av[j] = sigm(acc);
        }
        __syncthreads();
        #pragma unroll
        for (int j = 0; j < 2; ++j) {
            int tsk = tid + j*1024;
            int kind = tsk >> 10, o = tsk & 15, pos = (tsk >> 4) & 63;
            sG[kind*1024 + o*64 + pos] = av[j];
        }
    }
    __syncthreads();

    // ---- Pass A: x1 = x*ah*aw, per-channel sum + sumsq only (no-max softmax) ----
    {
        float s1[4] = {0.f,0.f,0.f,0.f}, q1[4] = {0.f,0.f,0.f,0.f};
        for (int k = 0; k < 16; ++k) {
            int tile = wv*16 + k;               // 0..255
            int hl = tile >> 2, wq = tile & 3;
            int w = wq*16 + col;
            const bf16x4 xv4 = *(const bf16x4*)&sX[XIDX(hl+1, w+1, qd*4)];
            #pragma unroll
            for (int r = 0; r < 4; ++r) {
                int c = qd*4 + r;
                float g = sG[c*64 + hl] * sG[1024 + c*64 + w];
                float x1v = bf2f((unsigned short)xv4[r]) * g;
                s1[r] += x1v; q1[r] = fmaf(x1v, x1v, q1[r]);
            }
        }
        #pragma unroll
        for (int m = 1; m < 16; m <<= 1) {
            #pragma unroll
            for (int r = 0; r < 4; ++r) {
                s1[r] += __shfl_xor(s1[r], m, 64);
                q1[r] += __shfl_xor(q1[r], m, 64);
            }
        }
        if (col == 0) {
            #pragma unroll
            for (int r = 0; r < 4; ++r) {
                sRedA[wv*16 + qd*4 + r] = s1[r];
                sRedB[wv*16 + qd*4 + r] = q1[r];
            }
        }
    }
    __syncthreads();
    if (tid < 16) {
        float s = 0.f, q = 0.f;
        for (int v2 = 0; v2 < 16; ++v2) { s += sRedA[v2*16 + tid]; q += sRedB[v2*16 + tid]; }
        sS1[tid] = s; sSQ[tid] = q;
    }
    __syncthreads();
    if (tid == 0) {
        float S = 0.f, Q = 0.f;
        for (int c = 0; c < 16; ++c) { S += sS1[c]; Q += sSQ[c]; }
        float mu = S * (1.0f/65536.0f);
        float var = Q * (1.0f/65536.0f) - mu*mu;
        sScal[0] = mu; sScal[1] = rsqrtf(var + 1e-5f);
    }
    __syncthreads();
    if (tid < 16) {
        float mu = sScal[0], rstd = sScal[1];
        float a  = gamma[tid] * rstd;
        float bb = beta[tid] - mu * a;                 // logit = a*x1 + bb (no max shift)
        sA[tid]  = a;
        sB1[tid] = bb;
        sV1[tid] = fmaf(a, sS1[tid] * (1.0f/4096.0f), bb);   // v1
    }
    __syncthreads();

    // ---- Pass B: single conv sweep, 4 chunks of 16 rows; Z1/Z3/S3; x3 -> LDS in-place ----
    {
        float aC[4], bC[4];
        #pragma unroll
        for (int r = 0; r < 4; ++r) { int c = qd*4 + r; aC[r] = sA[c]; bC[r] = sB1[c]; }
        float z1p[4] = {0.f,0.f,0.f,0.f}, z3p[4] = {0.f,0.f,0.f,0.f}, s3p[4] = {0.f,0.f,0.f,0.f};

        for (int c0 = 0; c0 < 4; ++c0) {
            unsigned int x3p[4][2];
            #pragma unroll
            for (int k = 0; k < 4; ++k) {
                int idx = wv*4 + k;             // 0..63 tiles in chunk
                int hl = idx >> 2, wq = idx & 3;
                int h = c0*16 + hl;
                int w = wq*16 + col;
                int base = XIDX(h+1, w+1, (qd & 1)*8);
                f32x4 acc = {0.f, 0.f, 0.f, 0.f};
                #pragma unroll
                for (int mm = 0; mm < 5; ++mm) {
                    const bf16x8 bfr = *(const bf16x8*)&sX[base + offs[mm]];
                    acc = __builtin_amdgcn_mfma_f32_16x16x32_bf16(afr[mm], bfr, acc, 0, 0, 0);
                }
                const bf16x4 xv4 = *(const bf16x4*)&sX[XIDX(h+1, w+1, qd*4)];
                unsigned short sb[4];
                #pragma unroll
                for (int r = 0; r < 4; ++r) {
                    float v = acc[r] + b3v[r];
                    float sv = v * sigm(v);
                    s3p[r] += sv;                          // v3 accumulates fp32 (matches ref path)
                    sb[r] = f2bf(sv);
                    z3p[r] += __expf(bf2f(sb[r]));         // denominator from the bf16-rounded value
                    int c = qd*4 + r;
                    float g = sG[c*64 + h] * sG[1024 + c*64 + w];
                    z1p[r] += __expf(fmaf(bf2f((unsigned short)xv4[r]), g*aC[r], bC[r]));
                }
                x3p[k][0] = (unsigned int)sb[0] | ((unsigned int)sb[1] << 16);
                x3p[k][1] = (unsigned int)sb[2] | ((unsigned int)sb[3] << 16);
            }
            __syncthreads();    // all chunk reads done -> safe to overwrite dead rows
            #pragma unroll
            for (int k = 0; k < 4; ++k) {
                int idx = wv*4 + k;
                int hl = idx >> 2, wq = idx & 3;
                int h = c0*16 + hl;
                int w = wq*16 + col;
                u32x2 pk = {x3p[k][0], x3p[k][1]};
                if (h >= 2) *(u32x2*)&sX[XIDX(h-1, w+1, qd*4)] = pk;   // slot row h-2 (h1 = h-1)
                else        *(u32x2*)&sXtra[(h*64 + w)*16 + qd*4] = pk;
            }
            // no barrier needed: next chunk reads rows >= 16c0+15, writes were <= 16c0+13
        }

        #pragma unroll
        for (int m = 1; m < 16; m <<= 1) {
            #pragma unroll
            for (int r = 0; r < 4; ++r) {
                z1p[r] += __shfl_xor(z1p[r], m, 64);
                z3p[r] += __shfl_xor(z3p[r], m, 64);
                s3p[r] += __shfl_xor(s3p[r], m, 64);
            }
        }
        if (col == 0) {
            #pragma unroll
            for (int r = 0; r < 4; ++r) {
                sRedA[wv*16 + qd*4 + r] = z1p[r];
                sRedB[wv*16 + qd*4 + r] = z3p[r];
                sRedC[wv*16 + qd*4 + r] = s3p[r];
            }
        }
    }
    __syncthreads();
    if (tid < 16) {
        float Z1 = 0.f, Z3 = 0.f, S3 = 0.f;
        for (int v2 = 0; v2 < 16; ++v2) {
            Z1 += sRedA[v2*16 + tid]; Z3 += sRedB[v2*16 + tid]; S3 += sRedC[v2*16 + tid];
        }
        sQ1[tid] = (S3 * (1.0f/4096.0f)) / Z1;   // v3 / Z1 (weights e1)
        sQ3[tid] = sV1[tid] / Z3;                // v1 / Z3 (weights e3)
    }
    __syncthreads();

    // ---- Pass C: pixel-contiguous final: s = sigmoid(sum_c q3*e3 + q1*e1); out = x*s ----
    // Each thread owns pixel p; all 16 channels. Global loads/stores: 16 x 256B
    // contiguous per wave instr. x3 from LDS in-place slots (2 x b128, 2-way).
    #pragma unroll
    for (int pp = 0; pp < 4; ++pp) {
        const int p = pp*1024 + tid;
        const int h = p >> 6;          // uniform per wave (p = pp*1024 + wv*64 + lane)
        const int w = p & 63;          // = lane
        bf16x8 x3a, x3b;
        if (h >= 2) {
            x3a = *(const bf16x8*)&sX[XIDX(h-1, w+1, 0)];
            x3b = *(const bf16x8*)&sX[XIDX(h-1, w+1, 8)];
        } else {
            x3a = *(const bf16x8*)&sXtra[(h*64 + w)*16 + 0];
            x3b = *(const bf16x8*)&sXtra[(h*64 + w)*16 + 8];
        }
        float xf[16];
        #pragma unroll
        for (int c = 0; c < 16; ++c) xf[c] = xg[c*4096 + p];
        float z = 0.f;
        #pragma unroll
        for (int c = 0; c < 16; ++c) {
            float e3 = __expf(bf2f((unsigned short)((c < 8) ? x3a[c] : x3b[c-8])));
            float g = sG[c*64 + h] * sG[1024 + c*64 + w];
            float xb = bf2f(f2bf(xf[c]));          // bf16-rounded: bit-identical logit to pass B
            float e1 = __expf(fmaf(xb, g*sA[c], sB1[c]));
            z = fmaf(sQ3[c], e3, fmaf(sQ1[c], e1, z));
        }
        float s = 1.0f / (1.0f + __expf(-z));
        #pragma unroll
        for (int c = 0; c < 16; ++c)
            ob[c*4096 + p] = xf[c] * s;
    }
}

extern "C" void kernel_launch(void* const* d_in, const int* in_sizes, int n_in,
                              void* d_out, int out_size, void* d_ws, size_t ws_size,
                              hipStream_t stream) {
    const float* x     = (const float*)d_in[0];
    const float* w1    = (const float*)d_in[1];
    const float* b1    = (const float*)d_in[2];
    const float* wh    = (const float*)d_in[3];
    const float* bh    = (const float*)d_in[4];
    const float* ww    = (const float*)d_in[5];
    const float* bw    = (const float*)d_in[6];
    const float* w3    = (const float*)d_in[7];
    const float* b3    = (const float*)d_in[8];
    const float* gamma = (const float*)d_in[9];
    const float* beta  = (const float*)d_in[10];
    hipLaunchKernelGGL(ema_fused, dim3(1024), dim3(1024), 0, stream,
                       x, w1, b1, wh, bh, ww, bw, w3, b3, gamma, beta, (float*)d_out);
}